// Round 11
// baseline (242.517 us; speedup 1.0000x reference)
//
#include <hip/hip_runtime.h>
#include <hip/hip_bf16.h>

// Problem constants
#define NB   8      // batch
#define NM   288    // Bkk = 32*3*3
#define NN   1152   // Cww = 32*6*6
#define NUV  36     // w*w
#define ND   16

// ws layout (float offsets; P/Wt regions hold bf16 in half the space)
#define OFF_P    0
#define SZ_P     (NB*NUV*NM*ND)      // patches, bf16 [b][uv][m][k*4+j]
#define OFF_WT   (OFF_P + SZ_P)
#define SZ_WT    (32*NM*ND)          // W transposed, bf16 [z][m][i*4+j]
#define OFF_ACT  (OFF_WT + SZ_WT)
#define SZ_ACT   (NB*NUV*NM)         // act LINEAR, f32 [b][uv][m]
#define OFF_L    (OFF_ACT + SZ_ACT)
#define SZ_L     (NB*NN*NM)          // A = ap (linear), f32 [b][n][m]
#define OFF_S    (OFF_L + SZ_L)
#define SZ_S     (NB*NM)             // S[b][m] = sum_n A
#define OFF_PS   (OFF_S + SZ_S)
#define SZ_PS    (NB*NUV*NM)         // sum stage-1 partials, [b][c][m]
#define OFF_FLAG (OFF_PS + SZ_PS)    // dtype flag

#define HALF_LOG_2PI 0.9189385332046727f
#define INV_NN       (1.0f/1152.0f)

__device__ __forceinline__ float ldin(const void* p, int i, int f32) {
    return f32 ? ((const float*)p)[i]
               : __bfloat162float(((const __hip_bfloat16*)p)[i]);
}

__device__ __forceinline__ float b2f(unsigned short u) {
    __hip_bfloat16 h = __builtin_bit_cast(__hip_bfloat16, u);
    return __bfloat162float(h);
}

__device__ __forceinline__ unsigned short bfbits(float f) {
    __hip_bfloat16 h = __float2bfloat16(f);
    return __builtin_bit_cast(unsigned short, h);
}

// packed bf16x2 dot with f32 accumulate: d = a.lo*b.lo + a.hi*b.hi + c
__device__ __forceinline__ float dot2bf(unsigned a, unsigned b, float c) {
    float d;
    asm("v_dot2_f32_bf16 %0, %1, %2, %3" : "=v"(d) : "v"(a), "v"(b), "v"(c));
    return d;
}

// inline dtype sniff (r3-r13 verified: flag==0 == bf16 on this harness)
__device__ __forceinline__ int sniff(const unsigned short* u16) {
    int wild = 0;
    for (int i = 0; i < 64; ++i) {
        int ex = (u16[i] >> 7) & 0xFF;
        if (ex >= 133) ++wild;
    }
    return (wild >= 4) ? 1 : 0;
}

// (b,s)-tiled prep: stage poses[b,:,s,:,:] + acts[b,s,:,:] in LDS, emit bf16 P
// (uint4 stores) and f32 act (LINEAR). Blocks 256..291 transpose W.
// bf16 FAST PATH vectorized (G13): pose staging 784 uint2 loads vs 3136
// scalar; W-transpose reads 2xuint4 (word layout already matches pk packing).
__global__ __launch_bounds__(256) void prep_kernel(
    const void* __restrict__ poses, const void* __restrict__ acts,
    const void* __restrict__ Wb, __hip_bfloat16* __restrict__ P,
    __hip_bfloat16* __restrict__ Wt, float* __restrict__ A36,
    int* __restrict__ flagw)
{
    const int blk = blockIdx.x;
    const int tid = threadIdx.x;
    __shared__ int lflag;
    if (tid == 0) {
        int f = sniff((const unsigned short*)poses);
        lflag = f;
        if (blk == 0) *flagw = f;
    }
    __syncthreads();
    const int f32 = lflag;

    if (blk < 256) {
        __shared__ float ps[16 * 196];
        __shared__ float asld[196];
        const int b = blk >> 5, s = blk & 31;
        if (!f32) {
            const unsigned short* pu = (const unsigned short*)poses;
            for (int e = tid; e < 784; e += 256) {
                int c = e / 49, off = (e % 49) * 4;
                size_t base = ((size_t)(b * 16 + c) * 32 + s) * 196 + off;
                uint2 q = *(const uint2*)(pu + base);   // 4 bf16, 8B aligned
                ps[c * 196 + off + 0] = b2f((unsigned short)(q.x & 0xffff));
                ps[c * 196 + off + 1] = b2f((unsigned short)(q.x >> 16));
                ps[c * 196 + off + 2] = b2f((unsigned short)(q.y & 0xffff));
                ps[c * 196 + off + 3] = b2f((unsigned short)(q.y >> 16));
            }
            const unsigned short* au = (const unsigned short*)acts;
            for (int e = tid; e < 49; e += 256) {
                int off = e * 4;
                uint2 q = *(const uint2*)(au + ((size_t)(b * 32 + s) * 196 + off));
                asld[off + 0] = b2f((unsigned short)(q.x & 0xffff));
                asld[off + 1] = b2f((unsigned short)(q.x >> 16));
                asld[off + 2] = b2f((unsigned short)(q.y & 0xffff));
                asld[off + 3] = b2f((unsigned short)(q.y >> 16));
            }
        } else {
            for (int e = tid; e < 16 * 196; e += 256) {
                int c = e / 196, hw = e % 196;
                ps[e] = ((const float*)poses)[((b * 16 + c) * 32 + s) * 196 + hw];
            }
            for (int e = tid; e < 196; e += 256)
                asld[e] = ((const float*)acts)[(b * 32 + s) * 196 + e];
        }
        __syncthreads();
        // P emit: 324 rows x 2 halves; one uint4 (8 bf16) per work item
        for (int o2 = tid; o2 < 648; o2 += 256) {
            int row = o2 >> 1, half = o2 & 1;
            int uv = row / 9, xy = row % 9;
            int u = uv / 6, vv2 = uv % 6;
            int x = xy / 3, y = xy % 3;
            unsigned pk[4];
#pragma unroll
            for (int h = 0; h < 4; ++h) {
                unsigned lohi[2];
#pragma unroll
                for (int e = 0; e < 2; ++e) {
                    int kj = half * 8 + h * 2 + e;
                    int k = kj >> 2, j = kj & 3;
                    int idx = u * 96 + vv2 * 16 + j * 4 + k;   // torch view scramble
                    int c = idx / 36, rem = idx % 36;
                    int wi = rem / 6, wj = rem % 6;
                    lohi[e] = bfbits(ps[c * 196 + (2 * wi + x) * 14 + (2 * wj + y)]);
                }
                pk[h] = lohi[0] | (lohi[1] << 16);
            }
            *((uint4*)(P + (((size_t)((b * 36 + uv) * 288 + s * 9 + xy)) << 4) + half * 8)) =
                make_uint4(pk[0], pk[1], pk[2], pk[3]);
        }
        for (int o = tid; o < 324; o += 256) {
            int uv = o / 9, xy = o % 9;
            int u = uv / 6, vv2 = uv % 6;
            int x = xy / 3, y = xy % 3;
            A36[(b * 36 + uv) * 288 + s * 9 + xy] =
                asld[(2 * u + x) * 14 + (2 * vv2 + y)];    // linear act
        }
    } else {
        int idx = (blk - 256) * 256 + tid;    // 0..9215 (z,m) pairs
        int z = idx / 288, m = idx % 288;
        uint4* dst = (uint4*)(Wt + idx * 16);
        if (!f32) {
            // 16 consecutive bf16 = 32B; word packing already (lo|hi<<16)
            const uint4* src = (const uint4*)((const unsigned short*)Wb + m * 512 + z * 16);
            dst[0] = src[0];
            dst[1] = src[1];
        } else {
            unsigned pk[8];
#pragma unroll
            for (int h = 0; h < 8; ++h) {
                unsigned lo = bfbits(((const float*)Wb)[m * 512 + z * 16 + 2 * h]);
                unsigned hi = bfbits(((const float*)Wb)[m * 512 + z * 16 + 2 * h + 1]);
                pk[h] = lo | (hi << 16);
            }
            dst[0] = make_uint4(pk[0], pk[1], pk[2], pk[3]);
            dst[1] = make_uint4(pk[4], pk[5], pk[6], pk[7]);
        }
    }
}

// 288-thread block (the winning shape — granularity ledger: r6 9-wave +34,
// r8 parallel-2n +45, r9 256+dual +7.8) processing TWO n SEQUENTIALLY
// (z and z+16 of the same g). All 6 global loads issue in the prologue, so
// task 1's load latency hides under task 0's compute; P row + act shared
// (same g); block-start ramp halves (4608 blocks). LDS reused serially —
// task1's red writes are fenced from task0's colsum by task0's barriers;
// task1's mul overwrite sits behind task1's B1/B2 (program order).
// Linear EM throughout (w = R*act; A = act*sum exp; no log/LSE).
// XCD swizzle: blockIdx = (g>>3)*128 + zp*8 + (g&7), g = b*36+uv, zp in [0,16).
__global__ __launch_bounds__(288, 4) void em_iter(
    const unsigned short* __restrict__ wsP, const unsigned short* __restrict__ wsWt,
    const float* __restrict__ wsA, float* __restrict__ wsL,
    const float* __restrict__ wsS,
    const void* __restrict__ beta_v,
    const void* __restrict__ beta_a,
    const void* __restrict__ lambda_,
    void* __restrict__ outv, const int* __restrict__ flagp, int iter)
{
    __shared__ float red[NM * 17];   // [m][col]: 0..15 = v[d], 16 = w  (19.6 KB)
    __shared__ float paru[NM];       // [d][c] partial sum(w*v)
    __shared__ float parv[NM];       // [d][c] partial sum(w*v*v)
    __shared__ float paruW[18];      // [c] partial sum(w)
    __shared__ float mul[16], nhil[16], ltl[16], ssl[16];

    const int tid = threadIdx.x;          // == m
    const int B   = blockIdx.x;
    const int rr  = B & 127;
    const int zp  = rr >> 3;                      // 0..15
    const int g   = ((B >> 7) << 3) | (rr & 7);   // b*36+uv
    const int b   = g / NUV;
    const int uv  = g % NUV;

    // all global loads for BOTH tasks issued up front
    const uint4* Pq = (const uint4*)(wsP + ((g * NM + tid) << 4));
    uint4 pq0 = Pq[0], pq1 = Pq[1];
    uint4 wq[2][2];
    int   bnv[2];
#pragma unroll
    for (int t = 0; t < 2; ++t) {
        const int z = zp + t * 16;
        bnv[t] = b * NN + z * NUV + uv;
        const uint4* Wq = (const uint4*)(wsWt + ((z * NM + tid) << 4));
        wq[t][0] = Wq[0];
        wq[t][1] = Wq[1];
    }
    const float act = wsA[g * NM + tid];   // linear act (shared: same g)
    float wv[2];
    if (iter == 0) {
        wv[0] = wv[1] = act * INV_NN;
    } else {
        float Sv = wsS[b * NM + tid];
        float ai = act / Sv;
        wv[0] = wsL[(size_t)bnv[0] * NM + tid] * ai;   // R*act, linear
        wv[1] = wsL[(size_t)bnv[1] * NM + tid] * ai;
    }

    unsigned Pa[4] = {pq0.x, pq0.z, pq1.x, pq1.z};
    unsigned Pb[4] = {pq0.y, pq0.w, pq1.y, pq1.w};

#pragma unroll
    for (int t = 0; t < 2; ++t) {
        const int bn = bnv[t];
        const int n  = bn - b * NN;
        const float w = wv[t];

        // votes v[i*4+k] = sum_j W[i][j] P[k-major][j] via packed bf16 dot2
        unsigned Wa[4]  = {wq[t][0].x, wq[t][0].z, wq[t][1].x, wq[t][1].z};
        unsigned Wb_[4] = {wq[t][0].y, wq[t][0].w, wq[t][1].y, wq[t][1].w};
        float v[16];
#pragma unroll
        for (int i = 0; i < 4; ++i)
#pragma unroll
            for (int k = 0; k < 4; ++k)
                v[i * 4 + k] = dot2bf(Wa[i], Pa[k], dot2bf(Wb_[i], Pb[k], 0.f));

        // transpose: m-major stride 17 (odd -> bank-bijective, 2-way = free)
#pragma unroll
        for (int dd = 0; dd < 16; ++dd) red[tid * 17 + dd] = v[dd];
        red[tid * 17 + 16] = w;
        __syncthreads();                                        // B1

        // column sums: thread (d = tid&15, c = tid>>4) sums m = 16c..16c+15
        {
            const int d = tid & 15, c = tid >> 4;
            const float* base = &red[(c << 4) * 17];
            float s1 = 0.f, s2 = 0.f, sw = 0.f;
#pragma unroll
            for (int q = 0; q < 16; ++q) {
                float ww = base[q * 17 + 16];
                float vv = base[q * 17 + d];
                float t1 = ww * vv;
                s1 += t1; s2 += t1 * vv; sw += ww;
            }
            paru[d * 18 + c] = s1;
            parv[d * 18 + c] = s2;
            if (d == 0) paruW[c] = sw;
        }
        __syncthreads();                                        // B2

        float sW_f = 0.f;   // live into the output stage (tid<16)
        if (tid < 16) {
            float sW = 0.f, S1 = 0.f, S2 = 0.f;
#pragma unroll
            for (int c = 0; c < 18; ++c) {
                sW += paruW[c];
                S1 += paru[tid * 18 + c];
                S2 += parv[tid * 18 + c];
            }
            float mu = S1 / sW;
            float q2 = S2 / sW;
            float ss = fmaxf(q2 - mu * mu, 1e-30f);   // E[v^2]-mu^2
            mul[tid]  = mu;
            ssl[tid]  = ss;
            nhil[tid] = -0.5f / ss;
            ltl[tid]  = fmaf(-0.5f, __logf(ss), -HALF_LOG_2PI);
            sW_f = sW;
        }
        __syncthreads();                                        // B3

        if (iter < 3) {
            // A[m] = act * sum_d exp(log_p_d)  — linear, like the reference
            float s = 0.f;
#pragma unroll
            for (int dd = 0; dd < 16; ++dd) {
                float df = v[dd] - mul[dd];
                s += __expf(fmaf(df * df, nhil[dd], ltl[dd]));
            }
            wsL[(size_t)bn * NM + tid] = act * s;   // contiguous store only
        } else {
            const int f32 = *flagp;
            if (tid < 16) {
                if (f32) ((float*)outv)[(bn << 4) + tid] = mul[tid];
                else ((__hip_bfloat16*)outv)[(bn << 4) + tid] = __float2bfloat16(mul[tid]);
            }
            if (tid == 0) {
                float sumR = sW_f;                 // true linear sum_R
                float bv = ldin(beta_v, n, f32);
                float c = 0.f;
#pragma unroll
                for (int dd = 0; dd < 16; ++dd) c += bv + __logf(ssl[dd]);
                c *= sumR;
                float lam = ldin(lambda_, 0, f32);
                float ba  = ldin(beta_a, n, f32);
                float ao  = 1.f / (1.f + __expf(-(lam * (ba - c))));
                int oi = NB * NN * ND + bn;
                if (f32) ((float*)outv)[oi] = ao;
                else ((__hip_bfloat16*)outv)[oi] = __float2bfloat16(ao);
            }
        }
    }
}

// sum stage 1: block (b,c) covers 32 rows n = 32c..32c+31 of contiguous
// A[b][n][m]; thread m walks the column (coalesced). Pure adds — one pass.
__global__ __launch_bounds__(288) void sum1_kernel(const float* __restrict__ L,
                                                   float* __restrict__ PS)
{
    const int tid = threadIdx.x;
    const int blk = blockIdx.x;           // b*36 + c
    const int b = blk / NUV;
    const int c = blk % NUV;
    const float* base = L + ((size_t)b * NN + c * 32) * NM + tid;
    float s = 0.f;
#pragma unroll
    for (int r = 0; r < 32; ++r) s += base[r * NM];
    PS[blk * NM + tid] = s;
}

// sum stage 2: combine 36 chunk partials per (b,m) row. 2304 rows.
__global__ void sum2_kernel(const float* __restrict__ PS,
                            float* __restrict__ S)
{
    int t = blockIdx.x * 256 + threadIdx.x;   // b*288 + m
    if (t >= NB * NM) return;
    int b = t / NM, m = t % NM;
    const float* ps = PS + (size_t)b * NUV * NM + m;
    float s = 0.f;
#pragma unroll
    for (int cc = 0; cc < NUV; ++cc) s += ps[cc * NM];
    S[t] = s;
}

extern "C" void kernel_launch(void* const* d_in, const int* in_sizes, int n_in,
                              void* d_out, int out_size, void* d_ws, size_t ws_size,
                              hipStream_t stream)
{
    const void* poses = d_in[0];
    const void* acts  = d_in[1];
    const void* lam   = d_in[2];
    const void* Wb    = d_in[3];
    const void* bv    = d_in[4];
    const void* ba    = d_in[5];

    float* ws  = (float*)d_ws;
    __hip_bfloat16* P  = (__hip_bfloat16*)(ws + OFF_P);
    __hip_bfloat16* Wt = (__hip_bfloat16*)(ws + OFF_WT);
    float* A36 = ws + OFF_ACT;
    float* L   = ws + OFF_L;
    float* S   = ws + OFF_S;
    float* PS  = ws + OFF_PS;
    int*  flag = (int*)(ws + OFF_FLAG);

    prep_kernel<<<292, 256, 0, stream>>>(poses, acts, Wb, P, Wt, A36, flag);

    for (int it = 0; it < 4; ++it) {
        em_iter<<<NB * NN / 2, 288, 0, stream>>>((const unsigned short*)P,
                                                 (const unsigned short*)Wt,
                                                 A36, L, S, bv, ba, lam,
                                                 d_out, flag, it);
        if (it < 3) {
            sum1_kernel<<<NB * NUV, 288, 0, stream>>>(L, PS);
            sum2_kernel<<<9, 256, 0, stream>>>(PS, S);
        }
    }
}

// Round 14
// 198.803 us; speedup vs baseline: 1.2199x; 1.2199x over previous
//
#include <hip/hip_runtime.h>
#include <hip/hip_bf16.h>

// Problem constants
#define NB   8      // batch
#define NM   288    // Bkk = 32*3*3
#define NN   1152   // Cww = 32*6*6
#define NUV  36     // w*w
#define ND   16

// ws layout (float offsets; P/Wt regions hold bf16 in half the space)
#define OFF_P    0
#define SZ_P     (NB*NUV*NM*ND)      // patches, bf16 [b][uv][m][k*4+j]
#define OFF_WT   (OFF_P + SZ_P)
#define SZ_WT    (32*NM*ND)          // W transposed, bf16 [z][m][i*4+j]
#define OFF_ACT  (OFF_WT + SZ_WT)
#define SZ_ACT   (NB*NUV*NM)         // act LINEAR, f32 [b][uv][m]
#define OFF_L    (OFF_ACT + SZ_ACT)
#define SZ_L     (NB*NN*NM)          // A = ap (linear), f32 [b][n][m]
#define OFF_S    (OFF_L + SZ_L)
#define SZ_S     (NB*NM)             // S[b][m] = sum_n A
#define OFF_PS   (OFF_S + SZ_S)
#define SZ_PS    (NB*NUV*NM)         // sum stage-1 partials, [b][c][m]
#define OFF_FLAG (OFF_PS + SZ_PS)    // dtype flag

#define HALF_LOG_2PI 0.9189385332046727f
#define INV_NN       (1.0f/1152.0f)

__device__ __forceinline__ float ldin(const void* p, int i, int f32) {
    return f32 ? ((const float*)p)[i]
               : __bfloat162float(((const __hip_bfloat16*)p)[i]);
}

__device__ __forceinline__ float b2f(unsigned short u) {
    __hip_bfloat16 h = __builtin_bit_cast(__hip_bfloat16, u);
    return __bfloat162float(h);
}

__device__ __forceinline__ unsigned short bfbits(float f) {
    __hip_bfloat16 h = __float2bfloat16(f);
    return __builtin_bit_cast(unsigned short, h);
}

// packed bf16x2 dot with f32 accumulate: d = a.lo*b.lo + a.hi*b.hi + c
__device__ __forceinline__ float dot2bf(unsigned a, unsigned b, float c) {
    float d;
    asm("v_dot2_f32_bf16 %0, %1, %2, %3" : "=v"(d) : "v"(a), "v"(b), "v"(c));
    return d;
}

// inline dtype sniff (r3-r13 verified: flag==0 == bf16 on this harness)
__device__ __forceinline__ int sniff(const unsigned short* u16) {
    int wild = 0;
    for (int i = 0; i < 64; ++i) {
        int ex = (u16[i] >> 7) & 0xFF;
        if (ex >= 133) ++wild;
    }
    return (wild >= 4) ? 1 : 0;
}

// (b,s)-tiled prep: stage poses[b,:,s,:,:] + acts[b,s,:,:] in LDS, emit bf16 P
// (uint4 stores) and f32 act (LINEAR). Blocks 256..291 transpose W.
// bf16 FAST PATH vectorized (G13 — hipcc never vectorizes scalar bf16):
// pose staging 784 uint2 loads (4 bf16, 8B-aligned: 196=49*4) vs 3136 scalar;
// W-transpose reads 2xuint4 (the word layout already matches pk packing).
__global__ __launch_bounds__(256) void prep_kernel(
    const void* __restrict__ poses, const void* __restrict__ acts,
    const void* __restrict__ Wb, __hip_bfloat16* __restrict__ P,
    __hip_bfloat16* __restrict__ Wt, float* __restrict__ A36,
    int* __restrict__ flagw)
{
    const int blk = blockIdx.x;
    const int tid = threadIdx.x;
    __shared__ int lflag;
    if (tid == 0) {
        int f = sniff((const unsigned short*)poses);
        lflag = f;
        if (blk == 0) *flagw = f;
    }
    __syncthreads();
    const int f32 = lflag;

    if (blk < 256) {
        __shared__ float ps[16 * 196];
        __shared__ float asld[196];
        const int b = blk >> 5, s = blk & 31;
        if (!f32) {
            const unsigned short* pu = (const unsigned short*)poses;
            for (int e = tid; e < 784; e += 256) {
                int c = e / 49, off = (e % 49) * 4;
                size_t base = ((size_t)(b * 16 + c) * 32 + s) * 196 + off;
                uint2 q = *(const uint2*)(pu + base);   // 4 bf16, 8B aligned
                ps[c * 196 + off + 0] = b2f((unsigned short)(q.x & 0xffff));
                ps[c * 196 + off + 1] = b2f((unsigned short)(q.x >> 16));
                ps[c * 196 + off + 2] = b2f((unsigned short)(q.y & 0xffff));
                ps[c * 196 + off + 3] = b2f((unsigned short)(q.y >> 16));
            }
            const unsigned short* au = (const unsigned short*)acts;
            for (int e = tid; e < 49; e += 256) {
                int off = e * 4;
                uint2 q = *(const uint2*)(au + ((size_t)(b * 32 + s) * 196 + off));
                asld[off + 0] = b2f((unsigned short)(q.x & 0xffff));
                asld[off + 1] = b2f((unsigned short)(q.x >> 16));
                asld[off + 2] = b2f((unsigned short)(q.y & 0xffff));
                asld[off + 3] = b2f((unsigned short)(q.y >> 16));
            }
        } else {
            for (int e = tid; e < 16 * 196; e += 256) {
                int c = e / 196, hw = e % 196;
                ps[e] = ((const float*)poses)[((b * 16 + c) * 32 + s) * 196 + hw];
            }
            for (int e = tid; e < 196; e += 256)
                asld[e] = ((const float*)acts)[(b * 32 + s) * 196 + e];
        }
        __syncthreads();
        // P emit: 324 rows x 2 halves; one uint4 (8 bf16) per work item
        for (int o2 = tid; o2 < 648; o2 += 256) {
            int row = o2 >> 1, half = o2 & 1;
            int uv = row / 9, xy = row % 9;
            int u = uv / 6, vv2 = uv % 6;
            int x = xy / 3, y = xy % 3;
            unsigned pk[4];
#pragma unroll
            for (int h = 0; h < 4; ++h) {
                unsigned lohi[2];
#pragma unroll
                for (int e = 0; e < 2; ++e) {
                    int kj = half * 8 + h * 2 + e;
                    int k = kj >> 2, j = kj & 3;
                    int idx = u * 96 + vv2 * 16 + j * 4 + k;   // torch view scramble
                    int c = idx / 36, rem = idx % 36;
                    int wi = rem / 6, wj = rem % 6;
                    lohi[e] = bfbits(ps[c * 196 + (2 * wi + x) * 14 + (2 * wj + y)]);
                }
                pk[h] = lohi[0] | (lohi[1] << 16);
            }
            *((uint4*)(P + (((size_t)((b * 36 + uv) * 288 + s * 9 + xy)) << 4) + half * 8)) =
                make_uint4(pk[0], pk[1], pk[2], pk[3]);
        }
        for (int o = tid; o < 324; o += 256) {
            int uv = o / 9, xy = o % 9;
            int u = uv / 6, vv2 = uv % 6;
            int x = xy / 3, y = xy % 3;
            A36[(b * 36 + uv) * 288 + s * 9 + xy] =
                asld[(2 * u + x) * 14 + (2 * vv2 + y)];    // linear act
        }
    } else {
        int idx = (blk - 256) * 256 + tid;    // 0..9215 (z,m) pairs
        int z = idx / 288, m = idx % 288;
        uint4* dst = (uint4*)(Wt + idx * 16);
        if (!f32) {
            // 16 consecutive bf16 = 32B; word packing already (lo|hi<<16)
            const uint4* src = (const uint4*)((const unsigned short*)Wb + m * 512 + z * 16);
            dst[0] = src[0];
            dst[1] = src[1];
        } else {
            unsigned pk[8];
#pragma unroll
            for (int h = 0; h < 8; ++h) {
                unsigned lo = bfbits(((const float*)Wb)[m * 512 + z * 16 + 2 * h]);
                unsigned hi = bfbits(((const float*)Wb)[m * 512 + z * 16 + 2 * h + 1]);
                pk[h] = lo | (hi << 16);
            }
            dst[0] = make_uint4(pk[0], pk[1], pk[2], pk[3]);
            dst[1] = make_uint4(pk[4], pk[5], pk[6], pk[7]);
        }
    }
}

// One block per (b,n), 288 threads — CHAMPION STRUCTURE (r10: 198.6 µs).
// Granularity ledger (all refuted): r6 9-wave +34, r8 parallel-2n +45,
// r9 256-thr slot-packing +7.8, r11 serial-2n +44, r12/r13 wave-per-n
// FAILED correctness. Many small loosely-coupled 4.5-wave blocks win.
// Linear EM throughout (w = R*act; A = act*sum exp; no log/LSE).
// XCD swizzle: blockIdx = (g>>3)*256 + z*8 + (g&7), g = b*36+uv.
__global__ __launch_bounds__(288, 4) void em_iter(
    const unsigned short* __restrict__ wsP, const unsigned short* __restrict__ wsWt,
    const float* __restrict__ wsA, float* __restrict__ wsL,
    const float* __restrict__ wsS,
    const void* __restrict__ beta_v,
    const void* __restrict__ beta_a,
    const void* __restrict__ lambda_,
    void* __restrict__ outv, const int* __restrict__ flagp, int iter)
{
    __shared__ float red[NM * 17];   // [m][col]: 0..15 = v[d], 16 = w  (19.6 KB)
    __shared__ float paru[NM];       // [d][c] partial sum(w*v)
    __shared__ float parv[NM];       // [d][c] partial sum(w*v*v)
    __shared__ float paruW[18];      // [c] partial sum(w)
    __shared__ float mul[16], nhil[16], ltl[16], ssl[16];

    const int tid = threadIdx.x;          // == m
    const int B   = blockIdx.x;
    const int rr  = B & 255;
    const int z   = rr >> 3;
    const int g   = ((B >> 8) << 3) | (rr & 7);   // b*36+uv
    const int b   = g / NUV;
    const int uv  = g % NUV;
    const int n   = z * NUV + uv;
    const int bn  = b * NN + n;

    // all global loads issued up front (bf16 W/P rows stay packed)
    const uint4* Wq = (const uint4*)(wsWt + ((z * NM + tid) << 4));
    const uint4* Pq = (const uint4*)(wsP + ((g * NM + tid) << 4));
    uint4 wq0 = Wq[0], wq1 = Wq[1];
    uint4 pq0 = Pq[0], pq1 = Pq[1];
    const float act = wsA[g * NM + tid];   // linear act
    float w;
    if (iter == 0) {
        w = act * INV_NN;
    } else {
        float Ap = wsL[(size_t)bn * NM + tid];
        float Sv = wsS[b * NM + tid];
        w = Ap * act / Sv;                 // R*act, linear (matches reference)
    }

    // votes v[i*4+k] = sum_j W[i][j] P[k-major][j] via packed bf16 dot2
    unsigned Wa[4]  = {wq0.x, wq0.z, wq1.x, wq1.z};   // (j0,j1) of i
    unsigned Wb_[4] = {wq0.y, wq0.w, wq1.y, wq1.w};   // (j2,j3) of i
    unsigned Pa[4]  = {pq0.x, pq0.z, pq1.x, pq1.z};   // (j0,j1) of k
    unsigned Pb[4]  = {pq0.y, pq0.w, pq1.y, pq1.w};   // (j2,j3) of k
    float v[16];
#pragma unroll
    for (int i = 0; i < 4; ++i)
#pragma unroll
        for (int k = 0; k < 4; ++k)
            v[i * 4 + k] = dot2bf(Wa[i], Pa[k], dot2bf(Wb_[i], Pb[k], 0.f));

    // transpose: m-major stride 17 (odd -> bank-bijective, 2-way = free)
#pragma unroll
    for (int dd = 0; dd < 16; ++dd) red[tid * 17 + dd] = v[dd];
    red[tid * 17 + 16] = w;
    __syncthreads();                                        // B1

    // column sums: thread (d = tid&15, c = tid>>4) sums m = 16c..16c+15
    {
        const int d = tid & 15, c = tid >> 4;
        const float* base = &red[(c << 4) * 17];
        float s1 = 0.f, s2 = 0.f, sw = 0.f;
#pragma unroll
        for (int q = 0; q < 16; ++q) {
            float ww = base[q * 17 + 16];
            float vv = base[q * 17 + d];
            float t1 = ww * vv;
            s1 += t1; s2 += t1 * vv; sw += ww;
        }
        paru[d * 18 + c] = s1;
        parv[d * 18 + c] = s2;
        if (d == 0) paruW[c] = sw;
    }
    __syncthreads();                                        // B2

    float sW_f = 0.f;   // live into the output stage (tid<16)
    if (tid < 16) {
        float sW = 0.f, S1 = 0.f, S2 = 0.f;
#pragma unroll
        for (int c = 0; c < 18; ++c) {
            sW += paruW[c];
            S1 += paru[tid * 18 + c];
            S2 += parv[tid * 18 + c];
        }
        float mu = S1 / sW;
        float q2 = S2 / sW;
        float ss = fmaxf(q2 - mu * mu, 1e-30f);   // E[v^2]-mu^2 (r4-r13 verified)
        mul[tid]  = mu;
        ssl[tid]  = ss;
        nhil[tid] = -0.5f / ss;
        ltl[tid]  = fmaf(-0.5f, __logf(ss), -HALF_LOG_2PI);
        sW_f = sW;
    }
    __syncthreads();                                        // B3

    if (iter < 3) {
        // A[m] = act * sum_d exp(log_p_d)  — linear, like the reference
        float s = 0.f;
#pragma unroll
        for (int dd = 0; dd < 16; ++dd) {
            float df = v[dd] - mul[dd];
            s += __expf(fmaf(df * df, nhil[dd], ltl[dd]));
        }
        wsL[(size_t)bn * NM + tid] = act * s;   // contiguous store only
    } else {
        const int f32 = *flagp;
        if (tid < 16) {
            if (f32) ((float*)outv)[(bn << 4) + tid] = mul[tid];
            else ((__hip_bfloat16*)outv)[(bn << 4) + tid] = __float2bfloat16(mul[tid]);
        }
        if (tid == 0) {
            float sumR = sW_f;                 // true linear sum_R
            float bv = ldin(beta_v, n, f32);
            float c = 0.f;
#pragma unroll
            for (int dd = 0; dd < 16; ++dd) c += bv + __logf(ssl[dd]);
            c *= sumR;
            float lam = ldin(lambda_, 0, f32);
            float ba  = ldin(beta_a, n, f32);
            float ao  = 1.f / (1.f + __expf(-(lam * (ba - c))));
            int oi = NB * NN * ND + bn;
            if (f32) ((float*)outv)[oi] = ao;
            else ((__hip_bfloat16*)outv)[oi] = __float2bfloat16(ao);
        }
    }
}

// sum stage 1: block (b,c) covers 32 rows n = 32c..32c+31 of contiguous
// A[b][n][m]; thread m walks the column (coalesced). Pure adds — one pass.
__global__ __launch_bounds__(288) void sum1_kernel(const float* __restrict__ L,
                                                   float* __restrict__ PS)
{
    const int tid = threadIdx.x;
    const int blk = blockIdx.x;           // b*36 + c
    const int b = blk / NUV;
    const int c = blk % NUV;
    const float* base = L + ((size_t)b * NN + c * 32) * NM + tid;
    float s = 0.f;
#pragma unroll
    for (int r = 0; r < 32; ++r) s += base[r * NM];
    PS[blk * NM + tid] = s;
}

// sum stage 2: combine 36 chunk partials per (b,m) row. 2304 rows.
__global__ void sum2_kernel(const float* __restrict__ PS,
                            float* __restrict__ S)
{
    int t = blockIdx.x * 256 + threadIdx.x;   // b*288 + m
    if (t >= NB * NM) return;
    int b = t / NM, m = t % NM;
    const float* ps = PS + (size_t)b * NUV * NM + m;
    float s = 0.f;
#pragma unroll
    for (int cc = 0; cc < NUV; ++cc) s += ps[cc * NM];
    S[t] = s;
}

extern "C" void kernel_launch(void* const* d_in, const int* in_sizes, int n_in,
                              void* d_out, int out_size, void* d_ws, size_t ws_size,
                              hipStream_t stream)
{
    const void* poses = d_in[0];
    const void* acts  = d_in[1];
    const void* lam   = d_in[2];
    const void* Wb    = d_in[3];
    const void* bv    = d_in[4];
    const void* ba    = d_in[5];

    float* ws  = (float*)d_ws;
    __hip_bfloat16* P  = (__hip_bfloat16*)(ws + OFF_P);
    __hip_bfloat16* Wt = (__hip_bfloat16*)(ws + OFF_WT);
    float* A36 = ws + OFF_ACT;
    float* L   = ws + OFF_L;
    float* S   = ws + OFF_S;
    float* PS  = ws + OFF_PS;
    int*  flag = (int*)(ws + OFF_FLAG);

    prep_kernel<<<292, 256, 0, stream>>>(poses, acts, Wb, P, Wt, A36, flag);

    for (int it = 0; it < 4; ++it) {
        em_iter<<<NB * NN, 288, 0, stream>>>((const unsigned short*)P,
                                             (const unsigned short*)Wt,
                                             A36, L, S, bv, ba, lam,
                                             d_out, flag, it);
        if (it < 3) {
            sum1_kernel<<<NB * NUV, 288, 0, stream>>>(L, PS);
            sum2_kernel<<<9, 256, 0, stream>>>(PS, S);
        }
    }
}

// Round 15
// 198.443 us; speedup vs baseline: 1.2221x; 1.0018x over previous
//
#include <hip/hip_runtime.h>
#include <hip/hip_bf16.h>

// Problem constants
#define NB   8      // batch
#define NM   288    // Bkk = 32*3*3
#define NN   1152   // Cww = 32*6*6
#define NUV  36     // w*w
#define ND   16

// ws layout (float offsets; P/Wt regions hold bf16 in half the space)
#define OFF_P    0
#define SZ_P     (NB*NUV*NM*ND)      // patches, bf16 [b][uv][m][k*4+j]
#define OFF_WT   (OFF_P + SZ_P)
#define SZ_WT    (32*NM*ND)          // W transposed, bf16 [z][m][i*4+j]
#define OFF_ACT  (OFF_WT + SZ_WT)
#define SZ_ACT   (NB*NUV*NM)         // act LINEAR, f32 [b][uv][m]
#define OFF_L    (OFF_ACT + SZ_ACT)
#define SZ_L     (NB*NN*NM)          // A = ap (linear), f32 [b][n][m]
#define OFF_S    (OFF_L + SZ_L)
#define SZ_S     (NB*NM)             // S[b][m] = sum_n A
#define OFF_PS   (OFF_S + SZ_S)
#define SZ_PS    (NB*NUV*NM)         // sum stage-1 partials, [b][c][m]
#define OFF_FLAG (OFF_PS + SZ_PS)    // dtype flag

#define HALF_LOG_2PI 0.9189385332046727f
#define INV_NN       (1.0f/1152.0f)

// column-major transpose buffer row stride: 292 floats.
// 292 % 4 == 0  -> every row 16B-aligned (b128-able for all d)
// 292 % 32 == 4 -> write banks (4d+lane)%32 2-way (free); b128 reads 2-way.
#define RSTR 292

__device__ __forceinline__ float ldin(const void* p, int i, int f32) {
    return f32 ? ((const float*)p)[i]
               : __bfloat162float(((const __hip_bfloat16*)p)[i]);
}

__device__ __forceinline__ float b2f(unsigned short u) {
    __hip_bfloat16 h = __builtin_bit_cast(__hip_bfloat16, u);
    return __bfloat162float(h);
}

__device__ __forceinline__ unsigned short bfbits(float f) {
    __hip_bfloat16 h = __float2bfloat16(f);
    return __builtin_bit_cast(unsigned short, h);
}

// packed bf16x2 dot with f32 accumulate: d = a.lo*b.lo + a.hi*b.hi + c
__device__ __forceinline__ float dot2bf(unsigned a, unsigned b, float c) {
    float d;
    asm("v_dot2_f32_bf16 %0, %1, %2, %3" : "=v"(d) : "v"(a), "v"(b), "v"(c));
    return d;
}

// inline dtype sniff (r3-r13 verified: flag==0 == bf16 on this harness)
__device__ __forceinline__ int sniff(const unsigned short* u16) {
    int wild = 0;
    for (int i = 0; i < 64; ++i) {
        int ex = (u16[i] >> 7) & 0xFF;
        if (ex >= 133) ++wild;
    }
    return (wild >= 4) ? 1 : 0;
}

// (b,s)-tiled prep: stage poses[b,:,s,:,:] + acts[b,s,:,:] in LDS, emit bf16 P
// (uint4 stores) and f32 act (LINEAR). Blocks 256..291 transpose W.
// bf16 FAST PATH vectorized (G13).
__global__ __launch_bounds__(256) void prep_kernel(
    const void* __restrict__ poses, const void* __restrict__ acts,
    const void* __restrict__ Wb, __hip_bfloat16* __restrict__ P,
    __hip_bfloat16* __restrict__ Wt, float* __restrict__ A36,
    int* __restrict__ flagw)
{
    const int blk = blockIdx.x;
    const int tid = threadIdx.x;
    __shared__ int lflag;
    if (tid == 0) {
        int f = sniff((const unsigned short*)poses);
        lflag = f;
        if (blk == 0) *flagw = f;
    }
    __syncthreads();
    const int f32 = lflag;

    if (blk < 256) {
        __shared__ float ps[16 * 196];
        __shared__ float asld[196];
        const int b = blk >> 5, s = blk & 31;
        if (!f32) {
            const unsigned short* pu = (const unsigned short*)poses;
            for (int e = tid; e < 784; e += 256) {
                int c = e / 49, off = (e % 49) * 4;
                size_t base = ((size_t)(b * 16 + c) * 32 + s) * 196 + off;
                uint2 q = *(const uint2*)(pu + base);   // 4 bf16, 8B aligned
                ps[c * 196 + off + 0] = b2f((unsigned short)(q.x & 0xffff));
                ps[c * 196 + off + 1] = b2f((unsigned short)(q.x >> 16));
                ps[c * 196 + off + 2] = b2f((unsigned short)(q.y & 0xffff));
                ps[c * 196 + off + 3] = b2f((unsigned short)(q.y >> 16));
            }
            const unsigned short* au = (const unsigned short*)acts;
            for (int e = tid; e < 49; e += 256) {
                int off = e * 4;
                uint2 q = *(const uint2*)(au + ((size_t)(b * 32 + s) * 196 + off));
                asld[off + 0] = b2f((unsigned short)(q.x & 0xffff));
                asld[off + 1] = b2f((unsigned short)(q.x >> 16));
                asld[off + 2] = b2f((unsigned short)(q.y & 0xffff));
                asld[off + 3] = b2f((unsigned short)(q.y >> 16));
            }
        } else {
            for (int e = tid; e < 16 * 196; e += 256) {
                int c = e / 196, hw = e % 196;
                ps[e] = ((const float*)poses)[((b * 16 + c) * 32 + s) * 196 + hw];
            }
            for (int e = tid; e < 196; e += 256)
                asld[e] = ((const float*)acts)[(b * 32 + s) * 196 + e];
        }
        __syncthreads();
        // P emit: 324 rows x 2 halves; one uint4 (8 bf16) per work item
        for (int o2 = tid; o2 < 648; o2 += 256) {
            int row = o2 >> 1, half = o2 & 1;
            int uv = row / 9, xy = row % 9;
            int u = uv / 6, vv2 = uv % 6;
            int x = xy / 3, y = xy % 3;
            unsigned pk[4];
#pragma unroll
            for (int h = 0; h < 4; ++h) {
                unsigned lohi[2];
#pragma unroll
                for (int e = 0; e < 2; ++e) {
                    int kj = half * 8 + h * 2 + e;
                    int k = kj >> 2, j = kj & 3;
                    int idx = u * 96 + vv2 * 16 + j * 4 + k;   // torch view scramble
                    int c = idx / 36, rem = idx % 36;
                    int wi = rem / 6, wj = rem % 6;
                    lohi[e] = bfbits(ps[c * 196 + (2 * wi + x) * 14 + (2 * wj + y)]);
                }
                pk[h] = lohi[0] | (lohi[1] << 16);
            }
            *((uint4*)(P + (((size_t)((b * 36 + uv) * 288 + s * 9 + xy)) << 4) + half * 8)) =
                make_uint4(pk[0], pk[1], pk[2], pk[3]);
        }
        for (int o = tid; o < 324; o += 256) {
            int uv = o / 9, xy = o % 9;
            int u = uv / 6, vv2 = uv % 6;
            int x = xy / 3, y = xy % 3;
            A36[(b * 36 + uv) * 288 + s * 9 + xy] =
                asld[(2 * u + x) * 14 + (2 * vv2 + y)];    // linear act
        }
    } else {
        int idx = (blk - 256) * 256 + tid;    // 0..9215 (z,m) pairs
        int z = idx / 288, m = idx % 288;
        uint4* dst = (uint4*)(Wt + idx * 16);
        if (!f32) {
            // 16 consecutive bf16 = 32B; word packing already (lo|hi<<16)
            const uint4* src = (const uint4*)((const unsigned short*)Wb + m * 512 + z * 16);
            dst[0] = src[0];
            dst[1] = src[1];
        } else {
            unsigned pk[8];
#pragma unroll
            for (int h = 0; h < 8; ++h) {
                unsigned lo = bfbits(((const float*)Wb)[m * 512 + z * 16 + 2 * h]);
                unsigned hi = bfbits(((const float*)Wb)[m * 512 + z * 16 + 2 * h + 1]);
                pk[h] = lo | (hi << 16);
            }
            dst[0] = make_uint4(pk[0], pk[1], pk[2], pk[3]);
            dst[1] = make_uint4(pk[4], pk[5], pk[6], pk[7]);
        }
    }
}

// One block per (b,n), 288 threads — champion structure (r10: 198.6 µs).
// r14 change (only): transpose buffer is COLUMN-MAJOR red2[17][RSTR] so the
// colsum stage reads contiguous 16-float runs via 8 ds_read_b128 instead of
// 32 ds_read_b32 (same q-order -> bit-identical sums). Writes stay 17 b32
// per thread, banks (4d+lane)%32 = 2-way (free).
// Linear EM throughout (w = R*act; A = act*sum exp; no log/LSE).
// XCD swizzle: blockIdx = (g>>3)*256 + z*8 + (g&7), g = b*36+uv.
__global__ __launch_bounds__(288, 4) void em_iter(
    const unsigned short* __restrict__ wsP, const unsigned short* __restrict__ wsWt,
    const float* __restrict__ wsA, float* __restrict__ wsL,
    const float* __restrict__ wsS,
    const void* __restrict__ beta_v,
    const void* __restrict__ beta_a,
    const void* __restrict__ lambda_,
    void* __restrict__ outv, const int* __restrict__ flagp, int iter)
{
    __shared__ __align__(16) float red2[17 * RSTR];  // [col][m], col 16 = w (19.9 KB)
    __shared__ float paru[NM];       // [d][c] partial sum(w*v)
    __shared__ float parv[NM];       // [d][c] partial sum(w*v*v)
    __shared__ float paruW[18];      // [c] partial sum(w)
    __shared__ float mul[16], nhil[16], ltl[16], ssl[16];

    const int tid = threadIdx.x;          // == m
    const int B   = blockIdx.x;
    const int rr  = B & 255;
    const int z   = rr >> 3;
    const int g   = ((B >> 8) << 3) | (rr & 7);   // b*36+uv
    const int b   = g / NUV;
    const int uv  = g % NUV;
    const int n   = z * NUV + uv;
    const int bn  = b * NN + n;

    // all global loads issued up front (bf16 W/P rows stay packed)
    const uint4* Wq = (const uint4*)(wsWt + ((z * NM + tid) << 4));
    const uint4* Pq = (const uint4*)(wsP + ((g * NM + tid) << 4));
    uint4 wq0 = Wq[0], wq1 = Wq[1];
    uint4 pq0 = Pq[0], pq1 = Pq[1];
    const float act = wsA[g * NM + tid];   // linear act
    float w;
    if (iter == 0) {
        w = act * INV_NN;
    } else {
        float Ap = wsL[(size_t)bn * NM + tid];
        float Sv = wsS[b * NM + tid];
        w = Ap * act / Sv;                 // R*act, linear (matches reference)
    }

    // votes v[i*4+k] = sum_j W[i][j] P[k-major][j] via packed bf16 dot2
    unsigned Wa[4]  = {wq0.x, wq0.z, wq1.x, wq1.z};   // (j0,j1) of i
    unsigned Wb_[4] = {wq0.y, wq0.w, wq1.y, wq1.w};   // (j2,j3) of i
    unsigned Pa[4]  = {pq0.x, pq0.z, pq1.x, pq1.z};   // (j0,j1) of k
    unsigned Pb[4]  = {pq0.y, pq0.w, pq1.y, pq1.w};   // (j2,j3) of k
    float v[16];
#pragma unroll
    for (int i = 0; i < 4; ++i)
#pragma unroll
        for (int k = 0; k < 4; ++k)
            v[i * 4 + k] = dot2bf(Wa[i], Pa[k], dot2bf(Wb_[i], Pb[k], 0.f));

    // transpose: column-major — thread m writes red2[dd][m] (banks 2-way free)
#pragma unroll
    for (int dd = 0; dd < 16; ++dd) red2[dd * RSTR + tid] = v[dd];
    red2[16 * RSTR + tid] = w;
    __syncthreads();                                        // B1

    // column sums: thread (d = tid&15, c = tid>>4) sums m = 16c..16c+15
    // via 4+4 ds_read_b128 (contiguous in the column-major layout).
    {
        const int d = tid & 15, c = tid >> 4;
        const float4* vr = (const float4*)(red2 + d * RSTR + (c << 4));
        const float4* wr = (const float4*)(red2 + 16 * RSTR + (c << 4));
        float s1 = 0.f, s2 = 0.f, sw = 0.f;
#pragma unroll
        for (int qq = 0; qq < 4; ++qq) {
            float4 vv = vr[qq];
            float4 ww = wr[qq];
            { float t = ww.x * vv.x; s1 += t; s2 += t * vv.x; sw += ww.x; }
            { float t = ww.y * vv.y; s1 += t; s2 += t * vv.y; sw += ww.y; }
            { float t = ww.z * vv.z; s1 += t; s2 += t * vv.z; sw += ww.z; }
            { float t = ww.w * vv.w; s1 += t; s2 += t * vv.w; sw += ww.w; }
        }
        paru[d * 18 + c] = s1;
        parv[d * 18 + c] = s2;
        if (d == 0) paruW[c] = sw;
    }
    __syncthreads();                                        // B2

    float sW_f = 0.f;   // live into the output stage (tid<16)
    if (tid < 16) {
        float sW = 0.f, S1 = 0.f, S2 = 0.f;
#pragma unroll
        for (int c = 0; c < 18; ++c) {
            sW += paruW[c];
            S1 += paru[tid * 18 + c];
            S2 += parv[tid * 18 + c];
        }
        float mu = S1 / sW;
        float q2 = S2 / sW;
        float ss = fmaxf(q2 - mu * mu, 1e-30f);   // E[v^2]-mu^2 (r4-r13 verified)
        mul[tid]  = mu;
        ssl[tid]  = ss;
        nhil[tid] = -0.5f / ss;
        ltl[tid]  = fmaf(-0.5f, __logf(ss), -HALF_LOG_2PI);
        sW_f = sW;
    }
    __syncthreads();                                        // B3

    if (iter < 3) {
        // A[m] = act * sum_d exp(log_p_d)  — linear, like the reference
        float s = 0.f;
#pragma unroll
        for (int dd = 0; dd < 16; ++dd) {
            float df = v[dd] - mul[dd];
            s += __expf(fmaf(df * df, nhil[dd], ltl[dd]));
        }
        wsL[(size_t)bn * NM + tid] = act * s;   // contiguous store only
    } else {
        const int f32 = *flagp;
        if (tid < 16) {
            if (f32) ((float*)outv)[(bn << 4) + tid] = mul[tid];
            else ((__hip_bfloat16*)outv)[(bn << 4) + tid] = __float2bfloat16(mul[tid]);
        }
        if (tid == 0) {
            float sumR = sW_f;                 // true linear sum_R
            float bv = ldin(beta_v, n, f32);
            float c = 0.f;
#pragma unroll
            for (int dd = 0; dd < 16; ++dd) c += bv + __logf(ssl[dd]);
            c *= sumR;
            float lam = ldin(lambda_, 0, f32);
            float ba  = ldin(beta_a, n, f32);
            float ao  = 1.f / (1.f + __expf(-(lam * (ba - c))));
            int oi = NB * NN * ND + bn;
            if (f32) ((float*)outv)[oi] = ao;
            else ((__hip_bfloat16*)outv)[oi] = __float2bfloat16(ao);
        }
    }
}

// sum stage 1: block (b,c) covers 32 rows n = 32c..32c+31 of contiguous
// A[b][n][m]; thread m walks the column (coalesced). Pure adds — one pass.
__global__ __launch_bounds__(288) void sum1_kernel(const float* __restrict__ L,
                                                   float* __restrict__ PS)
{
    const int tid = threadIdx.x;
    const int blk = blockIdx.x;           // b*36 + c
    const int b = blk / NUV;
    const int c = blk % NUV;
    const float* base = L + ((size_t)b * NN + c * 32) * NM + tid;
    float s = 0.f;
#pragma unroll
    for (int r = 0; r < 32; ++r) s += base[r * NM];
    PS[blk * NM + tid] = s;
}

// sum stage 2: combine 36 chunk partials per (b,m) row. 2304 rows.
__global__ void sum2_kernel(const float* __restrict__ PS,
                            float* __restrict__ S)
{
    int t = blockIdx.x * 256 + threadIdx.x;   // b*288 + m
    if (t >= NB * NM) return;
    int b = t / NM, m = t % NM;
    const float* ps = PS + (size_t)b * NUV * NM + m;
    float s = 0.f;
#pragma unroll
    for (int cc = 0; cc < NUV; ++cc) s += ps[cc * NM];
    S[t] = s;
}

extern "C" void kernel_launch(void* const* d_in, const int* in_sizes, int n_in,
                              void* d_out, int out_size, void* d_ws, size_t ws_size,
                              hipStream_t stream)
{
    const void* poses = d_in[0];
    const void* acts  = d_in[1];
    const void* lam   = d_in[2];
    const void* Wb    = d_in[3];
    const void* bv    = d_in[4];
    const void* ba    = d_in[5];

    float* ws  = (float*)d_ws;
    __hip_bfloat16* P  = (__hip_bfloat16*)(ws + OFF_P);
    __hip_bfloat16* Wt = (__hip_bfloat16*)(ws + OFF_WT);
    float* A36 = ws + OFF_ACT;
    float* L   = ws + OFF_L;
    float* S   = ws + OFF_S;
    float* PS  = ws + OFF_PS;
    int*  flag = (int*)(ws + OFF_FLAG);

    prep_kernel<<<292, 256, 0, stream>>>(poses, acts, Wb, P, Wt, A36, flag);

    for (int it = 0; it < 4; ++it) {
        em_iter<<<NB * NN, 288, 0, stream>>>((const unsigned short*)P,
                                             (const unsigned short*)Wt,
                                             A36, L, S, bv, ba, lam,
                                             d_out, flag, it);
        if (it < 3) {
            sum1_kernel<<<NB * NUV, 288, 0, stream>>>(L, PS);
            sum2_kernel<<<9, 256, 0, stream>>>(PS, S);
        }
    }
}